// Round 4
// baseline (480.861 us; speedup 1.0000x reference)
//
#include <hip/hip_runtime.h>

#define B_   16
#define C_   64
#define HW_  65536
#define CHW_ (C_ * HW_)   // 4194304 elements per batch
#define NT_  64           // n-tile per k1 step

typedef float f32x4 __attribute__((ext_vector_type(4)));

__device__ __forceinline__ float comp4(float4 v, int i) {
    return i == 0 ? v.x : i == 1 ? v.y : i == 2 ? v.z : v.w;
}

// ---------------------------------------------------------------------------
// Kernel 1 v2: partial Gram.  S[b,c,d] = sum_n X[b,c*HW+n] * Xflat[b,n*64+d]
// (unchanged from round 2)
// ---------------------------------------------------------------------------
__global__ __launch_bounds__(256, 4) void k1_gram(const float* __restrict__ x,
                                                  float* __restrict__ partial,
                                                  int nch, int nb) {
    const int ch   = blockIdx.x;
    const int b    = blockIdx.y;
    const int t    = threadIdx.x;
    const int w    = t >> 6;
    const int lane = t & 63;
    const int si   = lane >> 3;
    const int sj   = lane & 7;

    __shared__ float QsT[NT_][68];      // [n_local][c], pad 68
    __shared__ float Ks[NT_ * C_];      // [n_local][d] natural, flat

    float4 acc[8][2];
    #pragma unroll
    for (int r = 0; r < 8; r++) {
        acc[r][0] = make_float4(0.f, 0.f, 0.f, 0.f);
        acc[r][1] = make_float4(0.f, 0.f, 0.f, 0.f);
    }

    const float* xb = x + (size_t)b * CHW_;
    const int nA = t & 63;
    const int cq = t >> 6;

    for (int nt = ch * nb; nt < ch * nb + nb; nt += NT_) {
        __syncthreads();

        #pragma unroll
        for (int p = 0; p < 4; p++) {
            const int c = 4 * (cq + 4 * p);
            const float* qp = xb + (size_t)c * HW_ + nt + nA;
            float4 v;
            v.x = qp[0];
            v.y = qp[(size_t)1 * HW_];
            v.z = qp[(size_t)2 * HW_];
            v.w = qp[(size_t)3 * HW_];
            *(float4*)&QsT[nA][c] = v;
        }
        const float* kp = xb + (size_t)nt * C_;
        #pragma unroll
        for (int p = 0; p < 4; p++) {
            const int f = 4 * t + 1024 * p;
            *(float4*)&Ks[f] = *(const float4*)(kp + f);
        }
        __syncthreads();

        #pragma unroll
        for (int kk2 = 0; kk2 < 16; kk2++) {
            const int kk = 16 * w + kk2;
            const float4 q0  = *(const float4*)&QsT[kk][8 * si];
            const float4 q1  = *(const float4*)&QsT[kk][8 * si + 4];
            const float4 k0  = *(const float4*)&Ks[kk * C_ + 8 * sj];
            const float4 k1v = *(const float4*)&Ks[kk * C_ + 8 * sj + 4];
            #pragma unroll
            for (int r = 0; r < 8; r++) {
                const float qv = (r < 4) ? comp4(q0, r) : comp4(q1, r - 4);
                acc[r][0].x += qv * k0.x;
                acc[r][0].y += qv * k0.y;
                acc[r][0].z += qv * k0.z;
                acc[r][0].w += qv * k0.w;
                acc[r][1].x += qv * k1v.x;
                acc[r][1].y += qv * k1v.y;
                acc[r][1].z += qv * k1v.z;
                acc[r][1].w += qv * k1v.w;
            }
        }
    }

    __syncthreads();
    float* sred = Ks;
    for (int wr = 0; wr < 4; wr++) {
        if (w == wr) {
            #pragma unroll
            for (int r = 0; r < 8; r++) {
                const int idx = (8 * si + r) * 64 + 8 * sj;
                if (wr == 0) {
                    *(float4*)&sred[idx]     = acc[r][0];
                    *(float4*)&sred[idx + 4] = acc[r][1];
                } else {
                    float4 v0 = *(float4*)&sred[idx];
                    float4 v1 = *(float4*)&sred[idx + 4];
                    v0.x += acc[r][0].x; v0.y += acc[r][0].y;
                    v0.z += acc[r][0].z; v0.w += acc[r][0].w;
                    v1.x += acc[r][1].x; v1.y += acc[r][1].y;
                    v1.z += acc[r][1].z; v1.w += acc[r][1].w;
                    *(float4*)&sred[idx]     = v0;
                    *(float4*)&sred[idx + 4] = v1;
                }
            }
        }
        __syncthreads();
    }

    float* pb = partial + (size_t)(b * nch + ch) * 4096;
    for (int i = 4 * t; i < 4096; i += 1024)
        *(float4*)&pb[i] = *(const float4*)&sred[i];
}

// ---------------------------------------------------------------------------
// Kernel 2 v2: reduce partials + softmax (unchanged).
// Writes Mt[b,d,c] = softmax(S)[b,c,d] + (c==d).
// ---------------------------------------------------------------------------
__global__ __launch_bounds__(256) void k2_softmax(const float* __restrict__ partial,
                                                  float* __restrict__ mt, int nch) {
    const int c = blockIdx.x;
    const int b = blockIdx.y;
    const int t = threadIdx.x;
    const int w = t >> 6;
    const int d = t & 63;

    float s = 0.f;
    for (int ch = w; ch < nch; ch += 4)
        s += partial[(size_t)(b * nch + ch) * 4096 + c * 64 + d];

    __shared__ float red[256];
    red[t] = s;
    __syncthreads();
    if (w == 0) {
        s = red[d] + red[64 + d] + red[128 + d] + red[192 + d];
        float m = s;
        #pragma unroll
        for (int off = 32; off > 0; off >>= 1) m = fmaxf(m, __shfl_xor(m, off));
        const float e = expf(s - m);
        float sum = e;
        #pragma unroll
        for (int off = 32; off > 0; off >>= 1) sum += __shfl_xor(sum, off);
        mt[(size_t)b * 4096 + d * 64 + c] = e / sum + (c == d ? 1.f : 0.f);
    }
}

// ---------------------------------------------------------------------------
// Kernel 3 v3: out[b,c,n] = sum_d Mt[b,d,c] * X[b, d*HW + n]
// Explicit ping-pong register double-buffer: 4 x-loads always in flight
// while the other 4 d-slices compute (256 FMAs).  Fully unrolled d-loop.
// Nontemporal stores for out (free L2/L3 for x re-reads).
// ---------------------------------------------------------------------------
__global__ __launch_bounds__(256, 4) void k3_out(const float* __restrict__ x,
                                                 const float* __restrict__ mt,
                                                 float* __restrict__ out) {
    const int nb   = blockIdx.x;
    const int b    = blockIdx.y;
    const int t    = threadIdx.x;
    const int w    = t >> 6;
    const int lane = t & 63;

    __shared__ float Ms[64 * 64];   // Mt[d][c]
    {
        const float* mg = mt + (size_t)b * 4096;
        for (int i = 4 * t; i < 4096; i += 1024)
            *(float4*)&Ms[i] = *(const float4*)&mg[i];
    }
    __syncthreads();

    const int c0 = 16 * w;
    const size_t nbase = (size_t)nb * 256 + 4 * lane;
    const float* xp = x + (size_t)b * CHW_ + nbase;

    float4 acc[16];
    #pragma unroll
    for (int r = 0; r < 16; r++) acc[r] = make_float4(0.f, 0.f, 0.f, 0.f);

    float4 bufA[4], bufB[4];
    #pragma unroll
    for (int i = 0; i < 4; i++)
        bufA[i] = *(const float4*)(xp + (size_t)i * HW_);
    #pragma unroll
    for (int i = 0; i < 4; i++)
        bufB[i] = *(const float4*)(xp + (size_t)(4 + i) * HW_);

#define FMA_D(dd, xv)                                                        \
    {                                                                        \
        const float4 m0 = *(const float4*)&Ms[(dd) * 64 + c0];               \
        const float4 m1 = *(const float4*)&Ms[(dd) * 64 + c0 + 4];           \
        const float4 m2 = *(const float4*)&Ms[(dd) * 64 + c0 + 8];           \
        const float4 m3 = *(const float4*)&Ms[(dd) * 64 + c0 + 12];          \
        _Pragma("unroll")                                                    \
        for (int r = 0; r < 4; r++) {                                        \
            const float mv = comp4(m0, r);                                   \
            acc[r].x += mv * (xv).x; acc[r].y += mv * (xv).y;                \
            acc[r].z += mv * (xv).z; acc[r].w += mv * (xv).w;                \
        }                                                                    \
        _Pragma("unroll")                                                    \
        for (int r = 0; r < 4; r++) {                                        \
            const float mv = comp4(m1, r);                                   \
            acc[4 + r].x += mv * (xv).x; acc[4 + r].y += mv * (xv).y;        \
            acc[4 + r].z += mv * (xv).z; acc[4 + r].w += mv * (xv).w;        \
        }                                                                    \
        _Pragma("unroll")                                                    \
        for (int r = 0; r < 4; r++) {                                        \
            const float mv = comp4(m2, r);                                   \
            acc[8 + r].x += mv * (xv).x; acc[8 + r].y += mv * (xv).y;        \
            acc[8 + r].z += mv * (xv).z; acc[8 + r].w += mv * (xv).w;        \
        }                                                                    \
        _Pragma("unroll")                                                    \
        for (int r = 0; r < 4; r++) {                                        \
            const float mv = comp4(m3, r);                                   \
            acc[12 + r].x += mv * (xv).x; acc[12 + r].y += mv * (xv).y;      \
            acc[12 + r].z += mv * (xv).z; acc[12 + r].w += mv * (xv).w;      \
        }                                                                    \
    }

    #pragma unroll
    for (int d0 = 0; d0 < 64; d0 += 8) {
        // compute with bufA (d0..d0+3); bufB's loads are in flight
        #pragma unroll
        for (int i = 0; i < 4; i++) FMA_D(d0 + i, bufA[i]);
        if (d0 + 8 < 64) {
            #pragma unroll
            for (int i = 0; i < 4; i++)
                bufA[i] = *(const float4*)(xp + (size_t)(d0 + 8 + i) * HW_);
        }
        // compute with bufB (d0+4..d0+7); bufA's loads are in flight
        #pragma unroll
        for (int i = 0; i < 4; i++) FMA_D(d0 + 4 + i, bufB[i]);
        if (d0 + 12 < 64) {
            #pragma unroll
            for (int i = 0; i < 4; i++)
                bufB[i] = *(const float4*)(xp + (size_t)(d0 + 12 + i) * HW_);
        }
    }
#undef FMA_D

    #pragma unroll
    for (int r = 0; r < 16; r++) {
        f32x4* op = (f32x4*)(out + (size_t)b * CHW_ + (size_t)(c0 + r) * HW_ + nbase);
        f32x4 v;
        v.x = acc[r].x; v.y = acc[r].y; v.z = acc[r].z; v.w = acc[r].w;
        __builtin_nontemporal_store(v, op);
    }
}

// ---------------------------------------------------------------------------
extern "C" void kernel_launch(void* const* d_in, const int* in_sizes, int n_in,
                              void* d_out, int out_size, void* d_ws, size_t ws_size,
                              hipStream_t stream) {
    const float* x = (const float*)d_in[0];
    float* out = (float*)d_out;

    float* wsf     = (float*)d_ws;
    float* mt      = wsf;                          // B*4096 floats
    float* partial = wsf + (size_t)B_ * 4096;      // B*nch*4096 floats

    int nch = 128;
    while (nch > 1) {
        size_t need = (size_t)B_ * 4096 * sizeof(float)
                    + (size_t)B_ * nch * 4096 * sizeof(float);
        if (need <= ws_size) break;
        nch >>= 1;
    }
    const int nb = HW_ / nch;

    k1_gram<<<dim3(nch, B_), 256, 0, stream>>>(x, partial, nch, nb);
    k2_softmax<<<dim3(C_, B_), 256, 0, stream>>>(partial, mt, nch);
    k3_out<<<dim3(HW_ / 256, B_), 256, 0, stream>>>(x, mt, out);
}

// Round 5
// 272.176 us; speedup vs baseline: 1.7667x; 1.7667x over previous
//
#include <hip/hip_runtime.h>

#define B_   16
#define C_   64
#define HW_  65536
#define CHW_ (C_ * HW_)   // 4194304 elements per batch
#define NT_  64           // n-tile per k1 step

__device__ __forceinline__ float comp4(float4 v, int i) {
    return i == 0 ? v.x : i == 1 ? v.y : i == 2 ? v.z : v.w;
}

// ---------------------------------------------------------------------------
// Kernel 1 v2: partial Gram.  S[b,c,d] = sum_n X[b,c*HW+n] * Xflat[b,n*64+d]
// (unchanged from round 2)
// ---------------------------------------------------------------------------
__global__ __launch_bounds__(256, 4) void k1_gram(const float* __restrict__ x,
                                                  float* __restrict__ partial,
                                                  int nch, int nb) {
    const int ch   = blockIdx.x;
    const int b    = blockIdx.y;
    const int t    = threadIdx.x;
    const int w    = t >> 6;
    const int lane = t & 63;
    const int si   = lane >> 3;
    const int sj   = lane & 7;

    __shared__ float QsT[NT_][68];      // [n_local][c], pad 68
    __shared__ float Ks[NT_ * C_];      // [n_local][d] natural, flat

    float4 acc[8][2];
    #pragma unroll
    for (int r = 0; r < 8; r++) {
        acc[r][0] = make_float4(0.f, 0.f, 0.f, 0.f);
        acc[r][1] = make_float4(0.f, 0.f, 0.f, 0.f);
    }

    const float* xb = x + (size_t)b * CHW_;
    const int nA = t & 63;
    const int cq = t >> 6;

    for (int nt = ch * nb; nt < ch * nb + nb; nt += NT_) {
        __syncthreads();

        #pragma unroll
        for (int p = 0; p < 4; p++) {
            const int c = 4 * (cq + 4 * p);
            const float* qp = xb + (size_t)c * HW_ + nt + nA;
            float4 v;
            v.x = qp[0];
            v.y = qp[(size_t)1 * HW_];
            v.z = qp[(size_t)2 * HW_];
            v.w = qp[(size_t)3 * HW_];
            *(float4*)&QsT[nA][c] = v;
        }
        const float* kp = xb + (size_t)nt * C_;
        #pragma unroll
        for (int p = 0; p < 4; p++) {
            const int f = 4 * t + 1024 * p;
            *(float4*)&Ks[f] = *(const float4*)(kp + f);
        }
        __syncthreads();

        #pragma unroll
        for (int kk2 = 0; kk2 < 16; kk2++) {
            const int kk = 16 * w + kk2;
            const float4 q0  = *(const float4*)&QsT[kk][8 * si];
            const float4 q1  = *(const float4*)&QsT[kk][8 * si + 4];
            const float4 k0  = *(const float4*)&Ks[kk * C_ + 8 * sj];
            const float4 k1v = *(const float4*)&Ks[kk * C_ + 8 * sj + 4];
            #pragma unroll
            for (int r = 0; r < 8; r++) {
                const float qv = (r < 4) ? comp4(q0, r) : comp4(q1, r - 4);
                acc[r][0].x += qv * k0.x;
                acc[r][0].y += qv * k0.y;
                acc[r][0].z += qv * k0.z;
                acc[r][0].w += qv * k0.w;
                acc[r][1].x += qv * k1v.x;
                acc[r][1].y += qv * k1v.y;
                acc[r][1].z += qv * k1v.z;
                acc[r][1].w += qv * k1v.w;
            }
        }
    }

    __syncthreads();
    float* sred = Ks;
    for (int wr = 0; wr < 4; wr++) {
        if (w == wr) {
            #pragma unroll
            for (int r = 0; r < 8; r++) {
                const int idx = (8 * si + r) * 64 + 8 * sj;
                if (wr == 0) {
                    *(float4*)&sred[idx]     = acc[r][0];
                    *(float4*)&sred[idx + 4] = acc[r][1];
                } else {
                    float4 v0 = *(float4*)&sred[idx];
                    float4 v1 = *(float4*)&sred[idx + 4];
                    v0.x += acc[r][0].x; v0.y += acc[r][0].y;
                    v0.z += acc[r][0].z; v0.w += acc[r][0].w;
                    v1.x += acc[r][1].x; v1.y += acc[r][1].y;
                    v1.z += acc[r][1].z; v1.w += acc[r][1].w;
                    *(float4*)&sred[idx]     = v0;
                    *(float4*)&sred[idx + 4] = v1;
                }
            }
        }
        __syncthreads();
    }

    float* pb = partial + (size_t)(b * nch + ch) * 4096;
    for (int i = 4 * t; i < 4096; i += 1024)
        *(float4*)&pb[i] = *(const float4*)&sred[i];
}

// ---------------------------------------------------------------------------
// Kernel 2 v2: reduce partials + softmax (unchanged).
// Writes Mt[b,d,c] = softmax(S)[b,c,d] + (c==d).
// ---------------------------------------------------------------------------
__global__ __launch_bounds__(256) void k2_softmax(const float* __restrict__ partial,
                                                  float* __restrict__ mt, int nch) {
    const int c = blockIdx.x;
    const int b = blockIdx.y;
    const int t = threadIdx.x;
    const int w = t >> 6;
    const int d = t & 63;

    float s = 0.f;
    for (int ch = w; ch < nch; ch += 4)
        s += partial[(size_t)(b * nch + ch) * 4096 + c * 64 + d];

    __shared__ float red[256];
    red[t] = s;
    __syncthreads();
    if (w == 0) {
        s = red[d] + red[64 + d] + red[128 + d] + red[192 + d];
        float m = s;
        #pragma unroll
        for (int off = 32; off > 0; off >>= 1) m = fmaxf(m, __shfl_xor(m, off));
        const float e = expf(s - m);
        float sum = e;
        #pragma unroll
        for (int off = 32; off > 0; off >>= 1) sum += __shfl_xor(sum, off);
        mt[(size_t)b * 4096 + d * 64 + c] = e / sum + (c == d ? 1.f : 0.f);
    }
}

// ---------------------------------------------------------------------------
// Kernel 4 v4: out[b,c,n] = sum_d Mt[b,d,c] * X[b, d*HW + n]
// No LDS: M read via wave-uniform scalar loads (readfirstlane'd wave id ->
// s_load broadcasts from SGPRs).  Rolling 8-deep register prefetch of x with
// fully-unrolled d-loop (static buf indexing -> stays in VGPRs, ~1024 cyc
// of FMAs cover each load's latency).  Plain float4 stores.
// ---------------------------------------------------------------------------
__global__ __launch_bounds__(256, 4) void k3_out(const float* __restrict__ x,
                                                 const float* __restrict__ mt,
                                                 float* __restrict__ out) {
    const int nb   = blockIdx.x;
    const int b    = blockIdx.y;
    const int t    = threadIdx.x;
    const int w0   = __builtin_amdgcn_readfirstlane(t >> 6);  // wave-uniform
    const int lane = t & 63;

    const int c0 = 16 * w0;
    const size_t nbase = (size_t)nb * 256 + 4 * lane;
    const float* xp = x + (size_t)b * CHW_ + nbase;
    const float* mp = mt + (size_t)b * 4096 + c0;   // + d*64 + r, wave-uniform

    float4 acc[16];
    #pragma unroll
    for (int r = 0; r < 16; r++) acc[r] = make_float4(0.f, 0.f, 0.f, 0.f);

    float4 buf[8];
    #pragma unroll
    for (int i = 0; i < 8; i++)
        buf[i] = *(const float4*)(xp + (size_t)i * HW_);

    #pragma unroll
    for (int d = 0; d < 64; d++) {
        const float4 xv = buf[d & 7];
        if (d + 8 < 64)
            buf[d & 7] = *(const float4*)(xp + (size_t)(d + 8) * HW_);

        const float4 m0 = *(const float4*)(mp + d * 64);
        const float4 m1 = *(const float4*)(mp + d * 64 + 4);
        const float4 m2 = *(const float4*)(mp + d * 64 + 8);
        const float4 m3 = *(const float4*)(mp + d * 64 + 12);
        #pragma unroll
        for (int r = 0; r < 4; r++) {
            const float mv = comp4(m0, r);
            acc[r].x += mv * xv.x; acc[r].y += mv * xv.y;
            acc[r].z += mv * xv.z; acc[r].w += mv * xv.w;
        }
        #pragma unroll
        for (int r = 0; r < 4; r++) {
            const float mv = comp4(m1, r);
            acc[4 + r].x += mv * xv.x; acc[4 + r].y += mv * xv.y;
            acc[4 + r].z += mv * xv.z; acc[4 + r].w += mv * xv.w;
        }
        #pragma unroll
        for (int r = 0; r < 4; r++) {
            const float mv = comp4(m2, r);
            acc[8 + r].x += mv * xv.x; acc[8 + r].y += mv * xv.y;
            acc[8 + r].z += mv * xv.z; acc[8 + r].w += mv * xv.w;
        }
        #pragma unroll
        for (int r = 0; r < 4; r++) {
            const float mv = comp4(m3, r);
            acc[12 + r].x += mv * xv.x; acc[12 + r].y += mv * xv.y;
            acc[12 + r].z += mv * xv.z; acc[12 + r].w += mv * xv.w;
        }
    }

    #pragma unroll
    for (int r = 0; r < 16; r++)
        *(float4*)(out + (size_t)b * CHW_ + (size_t)(c0 + r) * HW_ + nbase) = acc[r];
}

// ---------------------------------------------------------------------------
extern "C" void kernel_launch(void* const* d_in, const int* in_sizes, int n_in,
                              void* d_out, int out_size, void* d_ws, size_t ws_size,
                              hipStream_t stream) {
    const float* x = (const float*)d_in[0];
    float* out = (float*)d_out;

    float* wsf     = (float*)d_ws;
    float* mt      = wsf;                          // B*4096 floats
    float* partial = wsf + (size_t)B_ * 4096;      // B*nch*4096 floats

    int nch = 128;
    while (nch > 1) {
        size_t need = (size_t)B_ * 4096 * sizeof(float)
                    + (size_t)B_ * nch * 4096 * sizeof(float);
        if (need <= ws_size) break;
        nch >>= 1;
    }
    const int nb = HW_ / nch;

    k1_gram<<<dim3(nch, B_), 256, 0, stream>>>(x, partial, nch, nb);
    k2_softmax<<<dim3(C_, B_), 256, 0, stream>>>(partial, mt, nch);
    k3_out<<<dim3(HW_ / 256, B_), 256, 0, stream>>>(x, mt, out);
}